// Round 1
// baseline (3995.732 us; speedup 1.0000x reference)
//
#include <hip/hip_runtime.h>
#include <cstdint>
#include <cstddef>

typedef _Float16 f16;
typedef _Float16 f16x8 __attribute__((ext_vector_type(8)));
typedef _Float16 f16x4 __attribute__((ext_vector_type(4)));
typedef float    f32x4 __attribute__((ext_vector_type(4)));

__device__ __forceinline__ void async_ld16(const f16* g, f16* l) {
  __builtin_amdgcn_global_load_lds(
      (const __attribute__((address_space(1))) void*)g,
      (__attribute__((address_space(3))) void*)l, 16, 0, 0);
}

// ---------------------------------------------------------------------------
// Conv 3x3 as implicit GEMM.  A = activations NHWC f16 (hi/lo), M = pixels.
// B = weights prepacked [tap][co][ci] f16 (hi/lo), N = co.  Cin = Cout = 512.
// NSPLIT=3: passes (aH*wH + aL*wH + aH*wL)  -> fp32-grade result.
// NSPLIT=1: single pass aH*wH.
// REFLECT: reflect-pad(1); else zero-pad(1) via zero-page gather.
// Output: out[b][pix][co] fp32 (NHWC), optionally accumulated.
// ---------------------------------------------------------------------------
template <int NSPLIT, bool REFLECT, bool ACCUM>
__global__ __launch_bounds__(256) void conv_gemm(
    const f16* __restrict__ aH, const f16* __restrict__ aL,
    const f16* __restrict__ wH, const f16* __restrict__ wL,
    float* __restrict__ out, const f16* __restrict__ zpage) {
  __shared__ f16 lsA[128 * 32];
  __shared__ f16 lsB[128 * 32];
  const int b = blockIdx.y;
  const int mt = blockIdx.x & 31;  // pixel tile (128 pixels = 2 image rows)
  const int nt = blockIdx.x >> 5;  // co tile
  const int tid = threadIdx.x;
  const int lane = tid & 63;
  const int wid = tid >> 6;
  const int wm = (wid >> 1) * 64;  // wave M offset
  const int wn = (wid & 1) * 64;   // wave N offset
  const int r4 = lane >> 2;        // staging row within 16
  const int scol = (lane & 3) * 8; // staging col (f16 elems)
  const int fr = lane & 15;        // frag row
  const int fk = (lane >> 4) * 8;  // frag k offset

  f32x4 acc[4][4];
#pragma unroll
  for (int i = 0; i < 4; ++i)
#pragma unroll
    for (int j = 0; j < 4; ++j) acc[i][j] = f32x4{0.f, 0.f, 0.f, 0.f};

  for (int p = 0; p < NSPLIT; ++p) {
    const f16* ab = (p == 1) ? aL : aH;
    const f16* wb = (p == 2) ? wL : wH;
    for (int tap = 0; tap < 9; ++tap) {
      const int dy = tap / 3 - 1;
      const int dx = tap % 3 - 1;
      const f16* ga[2];
      const f16* gw[2];
#pragma unroll
      for (int c = 0; c < 2; ++c) {
        int r = wid * 32 + c * 16 + r4;
        int pix = mt * 128 + r;
        int y = pix >> 6, x = pix & 63;
        int iy = y + dy, ix = x + dx;
        bool ok = true;
        if (REFLECT) {
          iy = (iy < 0) ? -iy : ((iy > 63) ? 126 - iy : iy);
          ix = (ix < 0) ? -ix : ((ix > 63) ? 126 - ix : ix);
        } else {
          ok = ((unsigned)iy < 64u) && ((unsigned)ix < 64u);
        }
        ga[c] = ok ? (ab + (((size_t)(b * 4096 + iy * 64 + ix)) << 9) + scol)
                   : zpage;
        int co = nt * 128 + r;
        gw[c] = wb + (((size_t)(tap * 512 + co)) << 9) + scol;
      }
      for (int ci0 = 0; ci0 < 512; ci0 += 32) {
        __syncthreads();  // all waves done reading previous chunk
#pragma unroll
        for (int c = 0; c < 2; ++c) {
          async_ld16(ga[c] + ci0, &lsA[(wid * 32 + c * 16) * 32]);
          async_ld16(gw[c] + ci0, &lsB[(wid * 32 + c * 16) * 32]);
        }
        __syncthreads();  // drains vmcnt -> LDS data visible
        f16x8 af[4], bfr[4];
#pragma unroll
        for (int i = 0; i < 4; ++i)
          af[i] = *(const f16x8*)&lsA[(wm + i * 16 + fr) * 32 + fk];
#pragma unroll
        for (int j = 0; j < 4; ++j)
          bfr[j] = *(const f16x8*)&lsB[(wn + j * 16 + fr) * 32 + fk];
#pragma unroll
        for (int i = 0; i < 4; ++i)
#pragma unroll
          for (int j = 0; j < 4; ++j)
            acc[i][j] = __builtin_amdgcn_mfma_f32_16x16x32_f16(
                af[i], bfr[j], acc[i][j], 0, 0, 0);
      }
    }
  }
  // epilogue: D[m=quad*4+reg][n=lane&15]
#pragma unroll
  for (int i = 0; i < 4; ++i) {
#pragma unroll
    for (int rg = 0; rg < 4; ++rg) {
      int m = mt * 128 + wm + i * 16 + (lane >> 4) * 4 + rg;
      size_t rowo = ((size_t)(b * 4096 + m)) << 9;
#pragma unroll
      for (int j = 0; j < 4; ++j) {
        int n = nt * 128 + wn + j * 16 + (lane & 15);
        float v = acc[i][j][rg];
        if (ACCUM)
          out[rowo + n] += v;
        else
          out[rowo + n] = v;
      }
    }
  }
}

// ---------------------------------------------------------------------------
// Patch Gram matrix: G[b][q][k] = sum_d xu[b][q][d]*xu[b][k][d], K=8192,
// fp16-split 3 passes.  xu layout: [b][patch(256)][d(8192)].
// ---------------------------------------------------------------------------
__global__ __launch_bounds__(256) void corr_gemm(const f16* __restrict__ xuH,
                                                 const f16* __restrict__ xuL,
                                                 float* __restrict__ G) {
  __shared__ f16 lsA[128 * 32];
  __shared__ f16 lsB[128 * 32];
  const int b = blockIdx.y;
  const int qt = blockIdx.x & 1;
  const int kt = blockIdx.x >> 1;
  const int tid = threadIdx.x;
  const int lane = tid & 63;
  const int wid = tid >> 6;
  const int wm = (wid >> 1) * 64;
  const int wn = (wid & 1) * 64;
  const int r4 = lane >> 2;
  const int scol = (lane & 3) * 8;
  const int fr = lane & 15;
  const int fk = (lane >> 4) * 8;

  f32x4 acc[4][4];
#pragma unroll
  for (int i = 0; i < 4; ++i)
#pragma unroll
    for (int j = 0; j < 4; ++j) acc[i][j] = f32x4{0.f, 0.f, 0.f, 0.f};

  for (int p = 0; p < 3; ++p) {
    const f16* ab = (p == 1) ? xuL : xuH;
    const f16* bb = (p == 2) ? xuL : xuH;
    const f16* ga[2];
    const f16* gb[2];
#pragma unroll
    for (int c = 0; c < 2; ++c) {
      int rr = wid * 32 + c * 16 + r4;
      ga[c] = ab + (((size_t)(b * 256 + qt * 128 + rr)) << 13) + scol;
      gb[c] = bb + (((size_t)(b * 256 + kt * 128 + rr)) << 13) + scol;
    }
    for (int d0 = 0; d0 < 8192; d0 += 32) {
      __syncthreads();
#pragma unroll
      for (int c = 0; c < 2; ++c) {
        async_ld16(ga[c] + d0, &lsA[(wid * 32 + c * 16) * 32]);
        async_ld16(gb[c] + d0, &lsB[(wid * 32 + c * 16) * 32]);
      }
      __syncthreads();
      f16x8 af[4], bfr[4];
#pragma unroll
      for (int i = 0; i < 4; ++i)
        af[i] = *(const f16x8*)&lsA[(wm + i * 16 + fr) * 32 + fk];
#pragma unroll
      for (int j = 0; j < 4; ++j)
        bfr[j] = *(const f16x8*)&lsB[(wn + j * 16 + fr) * 32 + fk];
#pragma unroll
      for (int i = 0; i < 4; ++i)
#pragma unroll
        for (int j = 0; j < 4; ++j)
          acc[i][j] = __builtin_amdgcn_mfma_f32_16x16x32_f16(af[i], bfr[j],
                                                             acc[i][j], 0, 0, 0);
    }
  }
#pragma unroll
  for (int i = 0; i < 4; ++i) {
#pragma unroll
    for (int rg = 0; rg < 4; ++rg) {
      int q = qt * 128 + wm + i * 16 + (lane >> 4) * 4 + rg;
      size_t rowo = ((size_t)(b * 256 + q)) << 8;
#pragma unroll
      for (int j = 0; j < 4; ++j) {
        int k = kt * 128 + wn + j * 16 + (lane & 15);
        G[rowo + k] = acc[i][j][rg];
      }
    }
  }
}

// --------------------------- elementwise kernels ---------------------------

// z NCHW fp32 -> NHWC f16 hi/lo (LDS tile transpose)
__global__ __launch_bounds__(256) void zsplit_transpose(
    const float* __restrict__ z, f16* __restrict__ zh, f16* __restrict__ zl) {
  __shared__ float t[64][65];
  const int pg = blockIdx.x, cg = blockIdx.y, b = blockIdx.z;
  const int tid = threadIdx.x;
#pragma unroll
  for (int it = 0; it < 16; ++it) {
    int idx = it * 256 + tid;
    int cr = idx >> 6, px = idx & 63;
    t[cr][px] = z[(((size_t)b * 512 + cg * 64 + cr) << 12) + pg * 64 + px];
  }
  __syncthreads();
#pragma unroll
  for (int it = 0; it < 16; ++it) {
    int idx = it * 256 + tid;
    int pr = idx >> 6, cc = idx & 63;
    float v = t[cc][pr];
    f16 h = (f16)v;
    size_t o = (((size_t)b * 4096 + pg * 64 + pr) << 9) + cg * 64 + cc;
    zh[o] = h;
    zl[o] = (f16)(v - (float)h);
  }
}

// OIHW fp32 -> [tap][co][ci] f16 hi/lo  (512x512x3x3)
__global__ void pack_w(const float* __restrict__ w, f16* __restrict__ wh,
                       f16* __restrict__ wl) {
  int i = blockIdx.x * 256 + threadIdx.x;
  if (i >= 9 * 512 * 512) return;
  int ci = i & 511, co = (i >> 9) & 511, tap = i >> 18;
  float v = w[((size_t)(co * 512 + ci)) * 9 + tap];
  f16 h = (f16)v;
  wh[i] = h;
  wl[i] = (f16)(v - (float)h);
}

// wf [512][1025][3][3] -> wfz/wfc [tap][co][ci<512] f16 hi/lo, wfm [co][tap] f32
__global__ void pack_wf_kernel(const float* __restrict__ wf, f16* __restrict__ wfzh,
                               f16* __restrict__ wfzl, f16* __restrict__ wfch,
                               f16* __restrict__ wfcl, float* __restrict__ wfm) {
  int i = blockIdx.x * 256 + threadIdx.x;
  if (i < 9 * 512 * 1024) {
    int ci = i & 1023, co = (i >> 10) & 511, tap = i >> 19;
    float v = wf[((size_t)co * 1025 + ci) * 9 + tap];
    f16 h = (f16)v;
    f16 l = (f16)(v - (float)h);
    int o = ((tap * 512 + co) << 9) + (ci & 511);
    if (ci < 512) {
      wfzh[o] = h;
      wfzl[o] = l;
    } else {
      wfch[o] = h;
      wfcl[o] = l;
    }
  } else {
    int j = i - 9 * 512 * 1024;
    if (j < 512 * 9) {
      int co = j / 9, tap = j - co * 9;
      wfm[j] = wf[((size_t)co * 1025 + 1024) * 9 + tap];
    }
  }
}

// bilinear-antialias resize + binarize == OR over 8x8 window
__global__ void mask_resize(const float* __restrict__ mask, float* __restrict__ M) {
  int i = blockIdx.x * 256 + threadIdx.x;
  if (i >= 16 * 4096) return;
  int b = i >> 12, oy = (i >> 6) & 63, ox = i & 63;
  int y0 = max(4 * oy - 2, 0), y1 = min(4 * oy + 5, 255);
  int x0 = max(4 * ox - 2, 0), x1 = min(4 * ox + 5, 255);
  const float* mb = mask + ((size_t)b << 16);
  float r = 0.f;
  for (int jy = y0; jy <= y1; ++jy) {
    for (int jx = x0; jx <= x1; ++jx) {
      if (mb[(jy << 8) + jx] != 0.f) {
        r = 1.f;
        jy = 256;
        break;
      }
    }
  }
  M[i] = r;
}

// non_mask flag per patch: count of ones in 4x4 >= 10
__global__ void patch_flag(const float* __restrict__ M, float* __restrict__ nonmask) {
  int i = blockIdx.x * 256 + threadIdx.x;
  if (i >= 16 * 256) return;
  int b = i >> 8, p = i & 255;
  int py = p >> 4, px = p & 15;
  int cnt = 0;
  for (int ki = 0; ki < 4; ++ki)
    for (int kj = 0; kj < 4; ++kj)
      cnt += (M[(b << 12) + ((py * 4 + ki) << 6) + px * 4 + kj] > 0.5f) ? 1 : 0;
  nonmask[i] = (cnt >= 10) ? 1.f : 0.f;
}

// InstanceNorm stats over pixels per (b,c) -> (mean, rstd).  Deterministic.
__global__ __launch_bounds__(256) void in_stats(const float* __restrict__ y,
                                                float2* __restrict__ stats) {
  const int cg = blockIdx.x, b = blockIdx.y;
  const int tid = threadIdx.x;
  const int cl = tid & 15, pr = tid >> 4;
  const int c = cg * 16 + cl;
  const float* base = y + (((size_t)b) << 21) + c;
  float s = 0.f, ss = 0.f;
  for (int pix = pr; pix < 4096; pix += 16) {
    float v = base[(size_t)pix << 9];
    s += v;
    ss += v * v;
  }
  __shared__ float s1[256], s2[256];
  s1[tid] = s;
  s2[tid] = ss;
  __syncthreads();
  for (int st = 128; st >= 16; st >>= 1) {
    if (tid < st) {
      s1[tid] += s1[tid + st];
      s2[tid] += s2[tid + st];
    }
    __syncthreads();
  }
  if (tid < 16) {
    float mean = s1[tid] * (1.f / 4096.f);
    float var = s2[tid] * (1.f / 4096.f) - mean * mean;
    stats[b * 512 + cg * 16 + tid] = make_float2(mean, 1.f / sqrtf(var + 1e-5f));
  }
}

// h1 = relu((y-mean)*rstd) -> f16 hi/lo  (NHWC, 4 elems/thread)
__global__ __launch_bounds__(256) void h_build(const float* __restrict__ y,
                                               const float2* __restrict__ stats,
                                               f16* __restrict__ hh,
                                               f16* __restrict__ hl) {
  size_t i = (size_t)blockIdx.x * 256 + threadIdx.x;
  if (i >= 8388608u) return;
  float4 v = ((const float4*)y)[i];
  size_t e = i << 2;
  int c = (int)(e & 511);
  int b = (int)(e >> 21);
  const float2* st = stats + b * 512 + c;
  float vv[4] = {v.x, v.y, v.z, v.w};
  f16x4 oh, ol;
#pragma unroll
  for (int j = 0; j < 4; ++j) {
    float2 s = st[j];
    float h = fmaxf((vv[j] - s.x) * s.y, 0.f);
    f16 hi = (f16)h;
    oh[j] = hi;
    ol[j] = (f16)(h - (float)hi);
  }
  ((f16x4*)hh)[i] = oh;
  ((f16x4*)hl)[i] = ol;
}

// x = z + (y2-mean)*rstd -> f16 hi/lo  (NHWC)
__global__ __launch_bounds__(256) void x_build(const float* __restrict__ y,
                                               const float2* __restrict__ stats,
                                               const f16* __restrict__ zh,
                                               const f16* __restrict__ zl,
                                               f16* __restrict__ xh,
                                               f16* __restrict__ xl) {
  size_t i = (size_t)blockIdx.x * 256 + threadIdx.x;
  if (i >= 8388608u) return;
  float4 v = ((const float4*)y)[i];
  f16x4 zhv = ((const f16x4*)zh)[i];
  f16x4 zlv = ((const f16x4*)zl)[i];
  size_t e = i << 2;
  int c = (int)(e & 511);
  int b = (int)(e >> 21);
  const float2* st = stats + b * 512 + c;
  float vv[4] = {v.x, v.y, v.z, v.w};
  f16x4 oh, ol;
#pragma unroll
  for (int j = 0; j < 4; ++j) {
    float2 s = st[j];
    float xv = (float)zhv[j] + (float)zlv[j] + (vv[j] - s.x) * s.y;
    f16 hi = (f16)xv;
    oh[j] = hi;
    ol[j] = (f16)(xv - (float)hi);
  }
  ((f16x4*)xh)[i] = oh;
  ((f16x4*)xl)[i] = ol;
}

// Build xu[b][patch][d] (d = c*16 + ki*4 + kj) f16 hi/lo + patch L2 norms.
__global__ __launch_bounds__(256) void xu_build(const f16* __restrict__ xh,
                                                const f16* __restrict__ xl,
                                                f16* __restrict__ xuh,
                                                f16* __restrict__ xul,
                                                float* __restrict__ norms) {
  __shared__ f16 lh[8192], ll[8192];
  __shared__ float red[256];
  const int p = blockIdx.x, b = blockIdx.y;
  const int tid = threadIdx.x;
  const int py = p >> 4, px = p & 15;
  const int po = tid >> 4, c0 = (tid & 15) * 32;
  const int ki = po >> 2, kj = po & 3;
  const size_t src =
      (((size_t)b * 4096 + (py * 4 + ki) * 64 + px * 4 + kj) << 9) + c0;
  float ss = 0.f;
#pragma unroll
  for (int v = 0; v < 4; ++v) {
    f16x8 a = *(const f16x8*)(xh + src + v * 8);
    f16x8 bb = *(const f16x8*)(xl + src + v * 8);
    *(f16x8*)&lh[po * 512 + c0 + v * 8] = a;
    *(f16x8*)&ll[po * 512 + c0 + v * 8] = bb;
#pragma unroll
    for (int k = 0; k < 8; ++k) {
      float t = (float)a[k] + (float)bb[k];
      ss += t * t;
    }
  }
  red[tid] = ss;
  __syncthreads();
  for (int st = 128; st >= 1; st >>= 1) {
    if (tid < st) red[tid] += red[tid + st];
    __syncthreads();
  }
  if (tid == 0) norms[b * 256 + p] = fmaxf(sqrtf(red[0]), 1e-12f);
  const size_t dst = (((size_t)(b * 256 + p)) << 13) + tid * 32;
#pragma unroll
  for (int v = 0; v < 4; ++v) {
    f16x8 oh, ol;
#pragma unroll
    for (int k = 0; k < 8; ++k) {
      int d = tid * 32 + v * 8 + k;
      int cc = d >> 4, poo = d & 15;
      oh[k] = lh[poo * 512 + cc];
      ol[k] = ll[poo * 512 + cc];
    }
    *(f16x8*)(xuh + dst + v * 8) = oh;
    *(f16x8*)(xul + dst + v * 8) = ol;
  }
}

// argmax_k of masked G[q][k]/norm_k, first-index tie-break
__global__ __launch_bounds__(256) void argmax_kernel(
    const float* __restrict__ G, const float* __restrict__ norms,
    const float* __restrict__ nonmask, int* __restrict__ marg) {
  const int q = blockIdx.x, b = blockIdx.y;
  const int t = threadIdx.x;
  float nm = nonmask[b * 256 + t];
  float v;
  if (nm == 1.f)
    v = -1e9f;
  else
    v = G[(((size_t)b * 256 + q) << 8) + t] / norms[b * 256 + t];
  __shared__ float bv[256];
  __shared__ int bi[256];
  bv[t] = v;
  bi[t] = t;
  __syncthreads();
  for (int st = 128; st >= 1; st >>= 1) {
    if (t < st) {
      float v2 = bv[t + st];
      int i2 = bi[t + st];
      if (v2 > bv[t] || (v2 == bv[t] && i2 < bi[t])) {
        bv[t] = v2;
        bi[t] = i2;
      }
    }
    __syncthreads();
  }
  if (t == 0) marg[b * 256 + q] = bi[0];
}

// composed_fold gather (hi only; final conv is single-pass f16)
__global__ void comp_build(const f16* __restrict__ xh, const int* __restrict__ marg,
                           f16* __restrict__ ch) {
  size_t i = (size_t)blockIdx.x * 256 + threadIdx.x;
  if (i >= (size_t)16 * 4096 * 64) return;
  int c8 = (int)(i & 63);
  int pix = (int)((i >> 6) & 4095);
  int b = (int)(i >> 18);
  int y = pix >> 6, x = pix & 63;
  int q = ((y >> 2) << 4) + (x >> 2);
  int k = marg[b * 256 + q];
  int sy = ((k >> 4) << 2) + (y & 3);
  int sx = ((k & 15) << 2) + (x & 3);
  size_t src = (((size_t)b * 4096 + sy * 64 + sx) << 9) + c8 * 8;
  size_t dst = (((size_t)b * 4096 + pix) << 9) + c8 * 8;
  *(f16x8*)(ch + dst) = *(const f16x8*)(xh + src);
}

// out NCHW = acc NHWC (transposed) + bias + 1-channel m-conv (zero pad)
__global__ __launch_bounds__(256) void finish_kernel(
    const float* __restrict__ acc, const float* __restrict__ wfm,
    const float* __restrict__ bias, const float* __restrict__ M,
    float* __restrict__ out) {
  __shared__ float ls[64][65];
  __shared__ float lw[64 * 9];
  __shared__ float lm[3][66];
  const int y = blockIdx.x, cg = blockIdx.y, b = blockIdx.z;
  const int tid = threadIdx.x;
#pragma unroll
  for (int it = 0; it < 16; ++it) {
    int idx = it * 256 + tid;
    int px = idx >> 6, co = idx & 63;
    ls[px][co] = acc[(((size_t)b * 4096 + y * 64 + px) << 9) + cg * 64 + co];
  }
  if (tid < 192) {
#pragma unroll
    for (int j = 0; j < 3; ++j) lw[tid * 3 + j] = wfm[(cg * 64) * 9 + tid * 3 + j];
  }
  if (tid < 198) {
    int row = tid / 66, col = tid % 66;
    int gy = y - 1 + row, gx = col - 1;
    float mv = 0.f;
    if ((unsigned)gy < 64u && (unsigned)gx < 64u)
      mv = M[(b << 12) + (gy << 6) + gx];
    lm[row][col] = mv;
  }
  __syncthreads();
#pragma unroll
  for (int it = 0; it < 16; ++it) {
    int idx = it * 256 + tid;
    int co = idx >> 6, px = idx & 63;
    float s = ls[px][co] + bias[cg * 64 + co];
#pragma unroll
    for (int ky = 0; ky < 3; ++ky)
#pragma unroll
      for (int kx = 0; kx < 3; ++kx)
        s += lw[co * 9 + ky * 3 + kx] * lm[ky][px + kx];
    out[(((size_t)b * 512 + cg * 64 + co) << 12) + y * 64 + px] = s;
  }
}

// ---------------------------------------------------------------------------
extern "C" void kernel_launch(void* const* d_in, const int* in_sizes, int n_in,
                              void* d_out, int out_size, void* d_ws,
                              size_t ws_size, hipStream_t stream) {
  const float* z = (const float*)d_in[0];
  const float* mask = (const float*)d_in[1];
  const float* w1 = (const float*)d_in[2];
  const float* w2 = (const float*)d_in[4];
  const float* wf = (const float*)d_in[6];
  const float* bfb = (const float*)d_in[7];
  float* out = (float*)d_out;

  char* ws = (char*)d_ws;
  size_t off = 0;
  auto alloc = [&](size_t bytes) -> void* {
    void* p = ws + off;
    off += (bytes + 255) & ~(size_t)255;
    return p;
  };
  f16* ZH = (f16*)alloc(67108864);
  f16* ZL = (f16*)alloc(67108864);
  f16* HXH = (f16*)alloc(67108864);  // h1 then x (hi)
  f16* HXL = (f16*)alloc(67108864);  // h1 then x (lo), then composed (hi)
  float* Y = (float*)alloc(134217728);  // y1 / y2 / final-conv accumulator; xu lives here between
  f16* W1H = (f16*)alloc(4718592);
  f16* W1L = (f16*)alloc(4718592);
  f16* W2H = (f16*)alloc(4718592);
  f16* W2L = (f16*)alloc(4718592);
  f16* WFZH = (f16*)alloc(4718592);
  f16* WFZL = (f16*)alloc(4718592);
  f16* WFCH = (f16*)alloc(4718592);
  f16* WFCL = (f16*)alloc(4718592);
  float* WFM = (float*)alloc(18432);
  float2* STATS = (float2*)alloc(65536);
  float* MBUF = (float*)alloc(262144);
  float* NONMASK = (float*)alloc(16384);
  float* G = (float*)alloc(4194304);
  float* NORMS = (float*)alloc(16384);
  int* MAXARG = (int*)alloc(16384);
  f16* ZPAGE = (f16*)alloc(4096);
  if (ws_size < off) return;  // workspace too small -> visible failure, no OOB

  f16* XUH = (f16*)Y;                        // 64 MB
  f16* XUL = (f16*)((char*)Y + 67108864);    // 64 MB

  hipMemsetAsync(ZPAGE, 0, 4096, stream);

  zsplit_transpose<<<dim3(64, 8, 16), 256, 0, stream>>>(z, ZH, ZL);
  pack_w<<<9216, 256, 0, stream>>>(w1, W1H, W1L);
  pack_w<<<9216, 256, 0, stream>>>(w2, W2H, W2L);
  pack_wf_kernel<<<18450, 256, 0, stream>>>(wf, WFZH, WFZL, WFCH, WFCL, WFM);
  mask_resize<<<256, 256, 0, stream>>>(mask, MBUF);
  patch_flag<<<16, 256, 0, stream>>>(MBUF, NONMASK);

  // conv1 -> y1
  conv_gemm<3, true, false><<<dim3(128, 16), 256, 0, stream>>>(ZH, ZL, W1H, W1L,
                                                               Y, ZPAGE);
  in_stats<<<dim3(32, 16), 256, 0, stream>>>(Y, STATS);
  h_build<<<32768, 256, 0, stream>>>(Y, STATS, HXH, HXL);
  // conv2 -> y2
  conv_gemm<3, true, false><<<dim3(128, 16), 256, 0, stream>>>(HXH, HXL, W2H,
                                                               W2L, Y, ZPAGE);
  in_stats<<<dim3(32, 16), 256, 0, stream>>>(Y, STATS);
  x_build<<<32768, 256, 0, stream>>>(Y, STATS, ZH, ZL, HXH, HXL);
  // patch attention
  xu_build<<<dim3(256, 16), 256, 0, stream>>>(HXH, HXL, XUH, XUL, NORMS);
  corr_gemm<<<dim3(4, 16), 256, 0, stream>>>(XUH, XUL, G);
  argmax_kernel<<<dim3(256, 16), 256, 0, stream>>>(G, NORMS, NONMASK, MAXARG);
  comp_build<<<16384, 256, 0, stream>>>(HXH, MAXARG, HXL);  // composed -> HXL
  // final conv: z part, composed part (accumulate), then m-channel + bias
  conv_gemm<1, false, false><<<dim3(128, 16), 256, 0, stream>>>(ZH, ZH, WFZH,
                                                                WFZH, Y, ZPAGE);
  conv_gemm<1, false, true><<<dim3(128, 16), 256, 0, stream>>>(HXL, HXL, WFCH,
                                                               WFCH, Y, ZPAGE);
  finish_kernel<<<dim3(64, 8, 16), 256, 0, stream>>>(Y, WFM, bfb, MBUF, out);
}

// Round 2
// 3708.186 us; speedup vs baseline: 1.0775x; 1.0775x over previous
//
#include <hip/hip_runtime.h>
#include <cstdint>
#include <cstddef>

typedef _Float16 f16;
typedef _Float16 f16x8 __attribute__((ext_vector_type(8)));
typedef _Float16 f16x4 __attribute__((ext_vector_type(4)));
typedef float    f32x4 __attribute__((ext_vector_type(4)));

__device__ __forceinline__ void async_ld16(const f16* g, f16* l) {
  __builtin_amdgcn_global_load_lds(
      (const __attribute__((address_space(1))) void*)g,
      (__attribute__((address_space(3))) void*)l, 16, 0, 0);
}

// ---------------------------------------------------------------------------
// Split-3 conv 3x3, pass-fused: per (tap, ci-chunk) stage aH,aL,wH,wL once,
// run HH + LH + HL combos = 48 MFMA per barrier-pair (vs 16 in round 1).
// Reflect-pad(1).  A NHWC f16 hi/lo, B [tap][co][ci] f16 hi/lo.
// out: [b][pix][co] fp32.
// ---------------------------------------------------------------------------
__global__ __launch_bounds__(256) void conv_fused3(
    const f16* __restrict__ aH, const f16* __restrict__ aL,
    const f16* __restrict__ wH, const f16* __restrict__ wL,
    float* __restrict__ out) {
  __shared__ f16 lsAH[4096], lsAL[4096], lsBH[4096], lsBL[4096];
  const int b = blockIdx.y;
  const int mt = blockIdx.x & 31;
  const int nt = blockIdx.x >> 5;
  const int tid = threadIdx.x;
  const int lane = tid & 63, wid = tid >> 6;
  const int wm = (wid >> 1) * 64, wn = (wid & 1) * 64;
  const int r4 = lane >> 2, scol = (lane & 3) * 8;
  const int fr = lane & 15, fk = (lane >> 4) * 8;

  f32x4 acc[4][4];
#pragma unroll
  for (int i = 0; i < 4; ++i)
#pragma unroll
    for (int j = 0; j < 4; ++j) acc[i][j] = f32x4{0.f, 0.f, 0.f, 0.f};

  for (int tap = 0; tap < 9; ++tap) {
    const int dy = tap / 3 - 1, dx = tap % 3 - 1;
    size_t offA[2], offW[2];
#pragma unroll
    for (int c = 0; c < 2; ++c) {
      int r = wid * 32 + c * 16 + r4;
      int pix = mt * 128 + r;
      int y = pix >> 6, x = pix & 63;
      int iy = y + dy, ix = x + dx;
      iy = (iy < 0) ? -iy : ((iy > 63) ? 126 - iy : iy);
      ix = (ix < 0) ? -ix : ((ix > 63) ? 126 - ix : ix);
      offA[c] = (((size_t)(b * 4096 + iy * 64 + ix)) << 9) + scol;
      offW[c] = (((size_t)(tap * 512 + nt * 128 + r)) << 9) + scol;
    }
    for (int ci0 = 0; ci0 < 512; ci0 += 32) {
      __syncthreads();
#pragma unroll
      for (int c = 0; c < 2; ++c) {
        f16* dA = (f16*)&lsAH[(wid * 32 + c * 16) * 32];
        async_ld16(aH + offA[c] + ci0, dA);
        async_ld16(aL + offA[c] + ci0, &lsAL[(wid * 32 + c * 16) * 32]);
        async_ld16(wH + offW[c] + ci0, &lsBH[(wid * 32 + c * 16) * 32]);
        async_ld16(wL + offW[c] + ci0, &lsBL[(wid * 32 + c * 16) * 32]);
      }
      __syncthreads();
      f16x8 ah[4], bh[4], t[4];
#pragma unroll
      for (int i = 0; i < 4; ++i)
        ah[i] = *(const f16x8*)&lsAH[(wm + i * 16 + fr) * 32 + fk];
#pragma unroll
      for (int j = 0; j < 4; ++j)
        bh[j] = *(const f16x8*)&lsBH[(wn + j * 16 + fr) * 32 + fk];
#pragma unroll
      for (int i = 0; i < 4; ++i)
#pragma unroll
        for (int j = 0; j < 4; ++j)
          acc[i][j] = __builtin_amdgcn_mfma_f32_16x16x32_f16(ah[i], bh[j],
                                                             acc[i][j], 0, 0, 0);
#pragma unroll
      for (int i = 0; i < 4; ++i)
        t[i] = *(const f16x8*)&lsAL[(wm + i * 16 + fr) * 32 + fk];
#pragma unroll
      for (int i = 0; i < 4; ++i)
#pragma unroll
        for (int j = 0; j < 4; ++j)
          acc[i][j] = __builtin_amdgcn_mfma_f32_16x16x32_f16(t[i], bh[j],
                                                             acc[i][j], 0, 0, 0);
#pragma unroll
      for (int j = 0; j < 4; ++j)
        t[j] = *(const f16x8*)&lsBL[(wn + j * 16 + fr) * 32 + fk];
#pragma unroll
      for (int i = 0; i < 4; ++i)
#pragma unroll
        for (int j = 0; j < 4; ++j)
          acc[i][j] = __builtin_amdgcn_mfma_f32_16x16x32_f16(ah[i], t[j],
                                                             acc[i][j], 0, 0, 0);
    }
  }
#pragma unroll
  for (int i = 0; i < 4; ++i) {
#pragma unroll
    for (int rg = 0; rg < 4; ++rg) {
      int m = mt * 128 + wm + i * 16 + (lane >> 4) * 4 + rg;
      size_t rowo = ((size_t)(b * 4096 + m)) << 9;
#pragma unroll
      for (int j = 0; j < 4; ++j) {
        int n = nt * 128 + wn + j * 16 + (lane & 15);
        out[rowo + n] = acc[i][j][rg];
      }
    }
  }
}

// ---------------------------------------------------------------------------
// Final conv, two sources fused (z-part + composed-part), single-pass f16,
// zero-pad(1).  Per (tap, ci-chunk): stage a0,a1,w0,w1 -> 32 MFMA/barrier.
// ---------------------------------------------------------------------------
__global__ __launch_bounds__(256) void conv_final2(
    const f16* __restrict__ a0, const f16* __restrict__ a1,
    const f16* __restrict__ w0, const f16* __restrict__ w1,
    float* __restrict__ out, const f16* __restrict__ zpage) {
  __shared__ f16 ls0A[4096], ls1A[4096], ls0B[4096], ls1B[4096];
  const int b = blockIdx.y;
  const int mt = blockIdx.x & 31;
  const int nt = blockIdx.x >> 5;
  const int tid = threadIdx.x;
  const int lane = tid & 63, wid = tid >> 6;
  const int wm = (wid >> 1) * 64, wn = (wid & 1) * 64;
  const int r4 = lane >> 2, scol = (lane & 3) * 8;
  const int fr = lane & 15, fk = (lane >> 4) * 8;

  f32x4 acc[4][4];
#pragma unroll
  for (int i = 0; i < 4; ++i)
#pragma unroll
    for (int j = 0; j < 4; ++j) acc[i][j] = f32x4{0.f, 0.f, 0.f, 0.f};

  for (int tap = 0; tap < 9; ++tap) {
    const int dy = tap / 3 - 1, dx = tap % 3 - 1;
    const f16* ga0[2];
    const f16* ga1[2];
    size_t offW[2];
#pragma unroll
    for (int c = 0; c < 2; ++c) {
      int r = wid * 32 + c * 16 + r4;
      int pix = mt * 128 + r;
      int y = pix >> 6, x = pix & 63;
      int iy = y + dy, ix = x + dx;
      bool ok = ((unsigned)iy < 64u) && ((unsigned)ix < 64u);
      size_t offA = (((size_t)(b * 4096 + iy * 64 + ix)) << 9) + scol;
      ga0[c] = ok ? (a0 + offA) : zpage;
      ga1[c] = ok ? (a1 + offA) : zpage;
      offW[c] = (((size_t)(tap * 512 + nt * 128 + r)) << 9) + scol;
    }
    for (int ci0 = 0; ci0 < 512; ci0 += 32) {
      __syncthreads();
#pragma unroll
      for (int c = 0; c < 2; ++c) {
        async_ld16(ga0[c] + ci0, &ls0A[(wid * 32 + c * 16) * 32]);
        async_ld16(ga1[c] + ci0, &ls1A[(wid * 32 + c * 16) * 32]);
        async_ld16(w0 + offW[c] + ci0, &ls0B[(wid * 32 + c * 16) * 32]);
        async_ld16(w1 + offW[c] + ci0, &ls1B[(wid * 32 + c * 16) * 32]);
      }
      __syncthreads();
      f16x8 af[4], bf[4];
#pragma unroll
      for (int i = 0; i < 4; ++i)
        af[i] = *(const f16x8*)&ls0A[(wm + i * 16 + fr) * 32 + fk];
#pragma unroll
      for (int j = 0; j < 4; ++j)
        bf[j] = *(const f16x8*)&ls0B[(wn + j * 16 + fr) * 32 + fk];
#pragma unroll
      for (int i = 0; i < 4; ++i)
#pragma unroll
        for (int j = 0; j < 4; ++j)
          acc[i][j] = __builtin_amdgcn_mfma_f32_16x16x32_f16(af[i], bf[j],
                                                             acc[i][j], 0, 0, 0);
#pragma unroll
      for (int i = 0; i < 4; ++i)
        af[i] = *(const f16x8*)&ls1A[(wm + i * 16 + fr) * 32 + fk];
#pragma unroll
      for (int j = 0; j < 4; ++j)
        bf[j] = *(const f16x8*)&ls1B[(wn + j * 16 + fr) * 32 + fk];
#pragma unroll
      for (int i = 0; i < 4; ++i)
#pragma unroll
        for (int j = 0; j < 4; ++j)
          acc[i][j] = __builtin_amdgcn_mfma_f32_16x16x32_f16(af[i], bf[j],
                                                             acc[i][j], 0, 0, 0);
    }
  }
#pragma unroll
  for (int i = 0; i < 4; ++i) {
#pragma unroll
    for (int rg = 0; rg < 4; ++rg) {
      int m = mt * 128 + wm + i * 16 + (lane >> 4) * 4 + rg;
      size_t rowo = ((size_t)(b * 4096 + m)) << 9;
#pragma unroll
      for (int j = 0; j < 4; ++j) {
        int n = nt * 128 + wn + j * 16 + (lane & 15);
        out[rowo + n] = acc[i][j][rg];
      }
    }
  }
}

// ---------------------------------------------------------------------------
// Patch Gram partials, K-split 4x, pass-fused (HH+LH+HL), gathering directly
// from x NHWC (d-axis permuted: d' = pixel_of_patch*512 + c — Gram-invariant).
// Gp layout: [ks][b][q][k] fp32.
// ---------------------------------------------------------------------------
__global__ __launch_bounds__(256) void corr_fused(const f16* __restrict__ xh,
                                                  const f16* __restrict__ xl,
                                                  float* __restrict__ Gp) {
  __shared__ f16 lsQH[4096], lsQL[4096], lsKH[4096], lsKL[4096];
  const int b = blockIdx.y;
  const int qt = blockIdx.x & 1, kt = (blockIdx.x >> 1) & 1, ks = blockIdx.x >> 2;
  const int tid = threadIdx.x;
  const int lane = tid & 63, wid = tid >> 6;
  const int wm = (wid >> 1) * 64, wn = (wid & 1) * 64;
  const int r4 = lane >> 2, scol = (lane & 3) * 8;
  const int fr = lane & 15, fk = (lane >> 4) * 8;

  f32x4 acc[4][4];
#pragma unroll
  for (int i = 0; i < 4; ++i)
#pragma unroll
    for (int j = 0; j < 4; ++j) acc[i][j] = f32x4{0.f, 0.f, 0.f, 0.f};

  for (int pp = 0; pp < 4; ++pp) {
    const int po = ks * 4 + pp;
    const int ki = po >> 2, kj = po & 3;
    size_t offQ[2], offK[2];
#pragma unroll
    for (int c = 0; c < 2; ++c) {
      int rr = wid * 32 + c * 16 + r4;
      int pq = qt * 128 + rr;
      int pk = kt * 128 + rr;
      int pixq = ((pq >> 4) * 4 + ki) * 64 + (pq & 15) * 4 + kj;
      int pixk = ((pk >> 4) * 4 + ki) * 64 + (pk & 15) * 4 + kj;
      offQ[c] = (((size_t)(b * 4096 + pixq)) << 9) + scol;
      offK[c] = (((size_t)(b * 4096 + pixk)) << 9) + scol;
    }
    for (int c0 = 0; c0 < 512; c0 += 32) {
      __syncthreads();
#pragma unroll
      for (int c = 0; c < 2; ++c) {
        async_ld16(xh + offQ[c] + c0, &lsQH[(wid * 32 + c * 16) * 32]);
        async_ld16(xl + offQ[c] + c0, &lsQL[(wid * 32 + c * 16) * 32]);
        async_ld16(xh + offK[c] + c0, &lsKH[(wid * 32 + c * 16) * 32]);
        async_ld16(xl + offK[c] + c0, &lsKL[(wid * 32 + c * 16) * 32]);
      }
      __syncthreads();
      f16x8 qh[4], kh[4], t[4];
#pragma unroll
      for (int i = 0; i < 4; ++i)
        qh[i] = *(const f16x8*)&lsQH[(wm + i * 16 + fr) * 32 + fk];
#pragma unroll
      for (int j = 0; j < 4; ++j)
        kh[j] = *(const f16x8*)&lsKH[(wn + j * 16 + fr) * 32 + fk];
#pragma unroll
      for (int i = 0; i < 4; ++i)
#pragma unroll
        for (int j = 0; j < 4; ++j)
          acc[i][j] = __builtin_amdgcn_mfma_f32_16x16x32_f16(qh[i], kh[j],
                                                             acc[i][j], 0, 0, 0);
#pragma unroll
      for (int i = 0; i < 4; ++i)
        t[i] = *(const f16x8*)&lsQL[(wm + i * 16 + fr) * 32 + fk];
#pragma unroll
      for (int i = 0; i < 4; ++i)
#pragma unroll
        for (int j = 0; j < 4; ++j)
          acc[i][j] = __builtin_amdgcn_mfma_f32_16x16x32_f16(t[i], kh[j],
                                                             acc[i][j], 0, 0, 0);
#pragma unroll
      for (int j = 0; j < 4; ++j)
        t[j] = *(const f16x8*)&lsKL[(wn + j * 16 + fr) * 32 + fk];
#pragma unroll
      for (int i = 0; i < 4; ++i)
#pragma unroll
        for (int j = 0; j < 4; ++j)
          acc[i][j] = __builtin_amdgcn_mfma_f32_16x16x32_f16(qh[i], t[j],
                                                             acc[i][j], 0, 0, 0);
    }
  }
#pragma unroll
  for (int i = 0; i < 4; ++i) {
#pragma unroll
    for (int rg = 0; rg < 4; ++rg) {
      int q = qt * 128 + wm + i * 16 + (lane >> 4) * 4 + rg;
      size_t rowo = ((size_t)((ks * 16 + b) * 256 + q)) << 8;
#pragma unroll
      for (int j = 0; j < 4; ++j) {
        int k = kt * 128 + wn + j * 16 + (lane & 15);
        Gp[rowo + k] = acc[i][j][rg];
      }
    }
  }
}

// --------------------------- elementwise kernels ---------------------------

__global__ __launch_bounds__(256) void zsplit_transpose(
    const float* __restrict__ z, f16* __restrict__ zh, f16* __restrict__ zl) {
  __shared__ float t[64][65];
  const int pg = blockIdx.x, cg = blockIdx.y, b = blockIdx.z;
  const int tid = threadIdx.x;
#pragma unroll
  for (int it = 0; it < 16; ++it) {
    int idx = it * 256 + tid;
    int cr = idx >> 6, px = idx & 63;
    t[cr][px] = z[(((size_t)b * 512 + cg * 64 + cr) << 12) + pg * 64 + px];
  }
  __syncthreads();
#pragma unroll
  for (int it = 0; it < 16; ++it) {
    int idx = it * 256 + tid;
    int pr = idx >> 6, cc = idx & 63;
    float v = t[cc][pr];
    f16 h = (f16)v;
    size_t o = (((size_t)b * 4096 + pg * 64 + pr) << 9) + cg * 64 + cc;
    zh[o] = h;
    zl[o] = (f16)(v - (float)h);
  }
}

__global__ void pack_w(const float* __restrict__ w, f16* __restrict__ wh,
                       f16* __restrict__ wl) {
  int i = blockIdx.x * 256 + threadIdx.x;
  if (i >= 9 * 512 * 512) return;
  int ci = i & 511, co = (i >> 9) & 511, tap = i >> 18;
  float v = w[((size_t)(co * 512 + ci)) * 9 + tap];
  f16 h = (f16)v;
  wh[i] = h;
  wl[i] = (f16)(v - (float)h);
}

// wf [512][1025][3][3] -> wfz/wfc [tap][co][ci<512] f16 hi, wfm [co][tap] f32
__global__ void pack_wf_kernel(const float* __restrict__ wf,
                               f16* __restrict__ wfz, f16* __restrict__ wfc,
                               float* __restrict__ wfm) {
  int i = blockIdx.x * 256 + threadIdx.x;
  if (i < 9 * 512 * 1024) {
    int ci = i & 1023, co = (i >> 10) & 511, tap = i >> 19;
    float v = wf[((size_t)co * 1025 + ci) * 9 + tap];
    f16 h = (f16)v;
    int o = ((tap * 512 + co) << 9) + (ci & 511);
    if (ci < 512)
      wfz[o] = h;
    else
      wfc[o] = h;
  } else {
    int j = i - 9 * 512 * 1024;
    if (j < 512 * 9) {
      int co = j / 9, tap = j - co * 9;
      wfm[j] = wf[((size_t)co * 1025 + 1024) * 9 + tap];
    }
  }
}

__global__ void mask_resize(const float* __restrict__ mask, float* __restrict__ M) {
  int i = blockIdx.x * 256 + threadIdx.x;
  if (i >= 16 * 4096) return;
  int b = i >> 12, oy = (i >> 6) & 63, ox = i & 63;
  int y0 = max(4 * oy - 2, 0), y1 = min(4 * oy + 5, 255);
  int x0 = max(4 * ox - 2, 0), x1 = min(4 * ox + 5, 255);
  const float* mb = mask + ((size_t)b << 16);
  float r = 0.f;
  for (int jy = y0; jy <= y1; ++jy) {
    for (int jx = x0; jx <= x1; ++jx) {
      if (mb[(jy << 8) + jx] != 0.f) {
        r = 1.f;
        jy = 256;
        break;
      }
    }
  }
  M[i] = r;
}

__global__ void patch_flag(const float* __restrict__ M, float* __restrict__ nonmask) {
  int i = blockIdx.x * 256 + threadIdx.x;
  if (i >= 16 * 256) return;
  int b = i >> 8, p = i & 255;
  int py = p >> 4, px = p & 15;
  int cnt = 0;
  for (int ki = 0; ki < 4; ++ki)
    for (int kj = 0; kj < 4; ++kj)
      cnt += (M[(b << 12) + ((py * 4 + ki) << 6) + px * 4 + kj] > 0.5f) ? 1 : 0;
  nonmask[i] = (cnt >= 10) ? 1.f : 0.f;
}

__global__ __launch_bounds__(256) void in_stats(const float* __restrict__ y,
                                                float2* __restrict__ stats) {
  const int cg = blockIdx.x, b = blockIdx.y;
  const int tid = threadIdx.x;
  const int cl = tid & 15, pr = tid >> 4;
  const int c = cg * 16 + cl;
  const float* base = y + (((size_t)b) << 21) + c;
  float s = 0.f, ss = 0.f;
  for (int pix = pr; pix < 4096; pix += 16) {
    float v = base[(size_t)pix << 9];
    s += v;
    ss += v * v;
  }
  __shared__ float s1[256], s2[256];
  s1[tid] = s;
  s2[tid] = ss;
  __syncthreads();
  for (int st = 128; st >= 16; st >>= 1) {
    if (tid < st) {
      s1[tid] += s1[tid + st];
      s2[tid] += s2[tid + st];
    }
    __syncthreads();
  }
  if (tid < 16) {
    float mean = s1[tid] * (1.f / 4096.f);
    float var = s2[tid] * (1.f / 4096.f) - mean * mean;
    stats[b * 512 + cg * 16 + tid] = make_float2(mean, 1.f / sqrtf(var + 1e-5f));
  }
}

__global__ __launch_bounds__(256) void h_build(const float* __restrict__ y,
                                               const float2* __restrict__ stats,
                                               f16* __restrict__ hh,
                                               f16* __restrict__ hl) {
  size_t i = (size_t)blockIdx.x * 256 + threadIdx.x;
  if (i >= 8388608u) return;
  float4 v = ((const float4*)y)[i];
  size_t e = i << 2;
  int c = (int)(e & 511);
  int b = (int)(e >> 21);
  const float2* st = stats + b * 512 + c;
  float vv[4] = {v.x, v.y, v.z, v.w};
  f16x4 oh, ol;
#pragma unroll
  for (int j = 0; j < 4; ++j) {
    float2 s = st[j];
    float h = fmaxf((vv[j] - s.x) * s.y, 0.f);
    f16 hi = (f16)h;
    oh[j] = hi;
    ol[j] = (f16)(h - (float)hi);
  }
  ((f16x4*)hh)[i] = oh;
  ((f16x4*)hl)[i] = ol;
}

__global__ __launch_bounds__(256) void x_build(const float* __restrict__ y,
                                               const float2* __restrict__ stats,
                                               const f16* __restrict__ zh,
                                               const f16* __restrict__ zl,
                                               f16* __restrict__ xh,
                                               f16* __restrict__ xl) {
  size_t i = (size_t)blockIdx.x * 256 + threadIdx.x;
  if (i >= 8388608u) return;
  float4 v = ((const float4*)y)[i];
  f16x4 zhv = ((const f16x4*)zh)[i];
  f16x4 zlv = ((const f16x4*)zl)[i];
  size_t e = i << 2;
  int c = (int)(e & 511);
  int b = (int)(e >> 21);
  const float2* st = stats + b * 512 + c;
  float vv[4] = {v.x, v.y, v.z, v.w};
  f16x4 oh, ol;
#pragma unroll
  for (int j = 0; j < 4; ++j) {
    float2 s = st[j];
    float xv = (float)zhv[j] + (float)zlv[j] + (vv[j] - s.x) * s.y;
    f16 hi = (f16)xv;
    oh[j] = hi;
    ol[j] = (f16)(xv - (float)hi);
  }
  ((f16x4*)xh)[i] = oh;
  ((f16x4*)xl)[i] = ol;
}

// Per-patch L2 norm of x (same summation order as round-1 xu_build).
__global__ __launch_bounds__(256) void patch_norms(const f16* __restrict__ xh,
                                                   const f16* __restrict__ xl,
                                                   float* __restrict__ norms) {
  __shared__ float red[256];
  const int p = blockIdx.x, b = blockIdx.y;
  const int tid = threadIdx.x;
  const int py = p >> 4, px = p & 15;
  const int po = tid >> 4, c0 = (tid & 15) * 32;
  const int ki = po >> 2, kj = po & 3;
  const size_t src =
      (((size_t)b * 4096 + (py * 4 + ki) * 64 + px * 4 + kj) << 9) + c0;
  float ss = 0.f;
#pragma unroll
  for (int v = 0; v < 4; ++v) {
    f16x8 a = *(const f16x8*)(xh + src + v * 8);
    f16x8 bb = *(const f16x8*)(xl + src + v * 8);
#pragma unroll
    for (int k = 0; k < 8; ++k) {
      float t = (float)a[k] + (float)bb[k];
      ss += t * t;
    }
  }
  red[tid] = ss;
  __syncthreads();
  for (int st = 128; st >= 1; st >>= 1) {
    if (tid < st) red[tid] += red[tid + st];
    __syncthreads();
  }
  if (tid == 0) norms[b * 256 + p] = fmaxf(sqrtf(red[0]), 1e-12f);
}

// argmax over k of (sum of 4 K-slice partials)/norm_k, masked; first-index tie.
__global__ __launch_bounds__(256) void argmax_kernel(
    const float* __restrict__ Gp, const float* __restrict__ norms,
    const float* __restrict__ nonmask, int* __restrict__ marg) {
  const int q = blockIdx.x, b = blockIdx.y;
  const int t = threadIdx.x;
  float nm = nonmask[b * 256 + t];
  float v;
  if (nm == 1.f) {
    v = -1e9f;
  } else {
    size_t o = (((size_t)b * 256 + q) << 8) + t;
    const size_t step = (size_t)16 * 256 * 256;
    double s = (double)Gp[o] + (double)Gp[o + step] + (double)Gp[o + 2 * step] +
               (double)Gp[o + 3 * step];
    v = (float)(s / (double)norms[b * 256 + t]);
  }
  __shared__ float bv[256];
  __shared__ int bi[256];
  bv[t] = v;
  bi[t] = t;
  __syncthreads();
  for (int st = 128; st >= 1; st >>= 1) {
    if (t < st) {
      float v2 = bv[t + st];
      int i2 = bi[t + st];
      if (v2 > bv[t] || (v2 == bv[t] && i2 < bi[t])) {
        bv[t] = v2;
        bi[t] = i2;
      }
    }
    __syncthreads();
  }
  if (t == 0) marg[b * 256 + q] = bi[0];
}

__global__ void comp_build(const f16* __restrict__ xh, const int* __restrict__ marg,
                           f16* __restrict__ ch) {
  size_t i = (size_t)blockIdx.x * 256 + threadIdx.x;
  if (i >= (size_t)16 * 4096 * 64) return;
  int c8 = (int)(i & 63);
  int pix = (int)((i >> 6) & 4095);
  int b = (int)(i >> 18);
  int y = pix >> 6, x = pix & 63;
  int q = ((y >> 2) << 4) + (x >> 2);
  int k = marg[b * 256 + q];
  int sy = ((k >> 4) << 2) + (y & 3);
  int sx = ((k & 15) << 2) + (x & 3);
  size_t src = (((size_t)b * 4096 + sy * 64 + sx) << 9) + c8 * 8;
  size_t dst = (((size_t)b * 4096 + pix) << 9) + c8 * 8;
  *(f16x8*)(ch + dst) = *(const f16x8*)(xh + src);
}

__global__ __launch_bounds__(256) void finish_kernel(
    const float* __restrict__ acc, const float* __restrict__ wfm,
    const float* __restrict__ bias, const float* __restrict__ M,
    float* __restrict__ out) {
  __shared__ float ls[64][65];
  __shared__ float lw[64 * 9];
  __shared__ float lm[3][66];
  const int y = blockIdx.x, cg = blockIdx.y, b = blockIdx.z;
  const int tid = threadIdx.x;
#pragma unroll
  for (int it = 0; it < 16; ++it) {
    int idx = it * 256 + tid;
    int px = idx >> 6, co = idx & 63;
    ls[px][co] = acc[(((size_t)b * 4096 + y * 64 + px) << 9) + cg * 64 + co];
  }
  if (tid < 192) {
#pragma unroll
    for (int j = 0; j < 3; ++j) lw[tid * 3 + j] = wfm[(cg * 64) * 9 + tid * 3 + j];
  }
  if (tid < 198) {
    int row = tid / 66, col = tid % 66;
    int gy = y - 1 + row, gx = col - 1;
    float mv = 0.f;
    if ((unsigned)gy < 64u && (unsigned)gx < 64u)
      mv = M[(b << 12) + (gy << 6) + gx];
    lm[row][col] = mv;
  }
  __syncthreads();
#pragma unroll
  for (int it = 0; it < 16; ++it) {
    int idx = it * 256 + tid;
    int co = idx >> 6, px = idx & 63;
    float s = ls[px][co] + bias[cg * 64 + co];
#pragma unroll
    for (int ky = 0; ky < 3; ++ky)
#pragma unroll
      for (int kx = 0; kx < 3; ++kx)
        s += lw[co * 9 + ky * 3 + kx] * lm[ky][px + kx];
    out[(((size_t)b * 512 + cg * 64 + co) << 12) + y * 64 + px] = s;
  }
}

// ---------------------------------------------------------------------------
extern "C" void kernel_launch(void* const* d_in, const int* in_sizes, int n_in,
                              void* d_out, int out_size, void* d_ws,
                              size_t ws_size, hipStream_t stream) {
  const float* z = (const float*)d_in[0];
  const float* mask = (const float*)d_in[1];
  const float* w1 = (const float*)d_in[2];
  const float* w2 = (const float*)d_in[4];
  const float* wf = (const float*)d_in[6];
  const float* bfb = (const float*)d_in[7];
  float* out = (float*)d_out;

  char* ws = (char*)d_ws;
  size_t off = 0;
  auto alloc = [&](size_t bytes) -> void* {
    void* p = ws + off;
    off += (bytes + 255) & ~(size_t)255;
    return p;
  };
  f16* ZH = (f16*)alloc(67108864);
  f16* ZL = (f16*)alloc(67108864);   // G partials alias here after x_build
  f16* HXH = (f16*)alloc(67108864);  // h1 then x (hi)
  f16* HXL = (f16*)alloc(67108864);  // h1/x (lo), then composed (hi)
  float* Y = (float*)alloc(134217728);
  f16* W1H = (f16*)alloc(4718592);
  f16* W1L = (f16*)alloc(4718592);
  f16* W2H = (f16*)alloc(4718592);
  f16* W2L = (f16*)alloc(4718592);
  f16* WFZ = (f16*)alloc(4718592);
  f16* WFC = (f16*)alloc(4718592);
  float* WFM = (float*)alloc(18432);
  float2* STATS = (float2*)alloc(65536);
  float* MBUF = (float*)alloc(262144);
  float* NONMASK = (float*)alloc(16384);
  float* NORMS = (float*)alloc(16384);
  int* MAXARG = (int*)alloc(16384);
  f16* ZPAGE = (f16*)alloc(4096);
  if (ws_size < off) return;

  float* G = (float*)ZL;  // 16.8 MB of 64 MB, live only corr->argmax

  hipMemsetAsync(ZPAGE, 0, 4096, stream);

  zsplit_transpose<<<dim3(64, 8, 16), 256, 0, stream>>>(z, ZH, ZL);
  pack_w<<<9216, 256, 0, stream>>>(w1, W1H, W1L);
  pack_w<<<9216, 256, 0, stream>>>(w2, W2H, W2L);
  pack_wf_kernel<<<18450, 256, 0, stream>>>(wf, WFZ, WFC, WFM);
  mask_resize<<<256, 256, 0, stream>>>(mask, MBUF);
  patch_flag<<<16, 256, 0, stream>>>(MBUF, NONMASK);

  conv_fused3<<<dim3(128, 16), 256, 0, stream>>>(ZH, ZL, W1H, W1L, Y);
  in_stats<<<dim3(32, 16), 256, 0, stream>>>(Y, STATS);
  h_build<<<32768, 256, 0, stream>>>(Y, STATS, HXH, HXL);
  conv_fused3<<<dim3(128, 16), 256, 0, stream>>>(HXH, HXL, W2H, W2L, Y);
  in_stats<<<dim3(32, 16), 256, 0, stream>>>(Y, STATS);
  x_build<<<32768, 256, 0, stream>>>(Y, STATS, ZH, ZL, HXH, HXL);

  patch_norms<<<dim3(256, 16), 256, 0, stream>>>(HXH, HXL, NORMS);
  corr_fused<<<dim3(16, 16), 256, 0, stream>>>(HXH, HXL, G);
  argmax_kernel<<<dim3(256, 16), 256, 0, stream>>>(G, NORMS, NONMASK, MAXARG);
  comp_build<<<16384, 256, 0, stream>>>(HXH, MAXARG, HXL);

  conv_final2<<<dim3(128, 16), 256, 0, stream>>>(ZH, HXL, WFZ, WFC, Y, ZPAGE);
  finish_kernel<<<dim3(64, 8, 16), 256, 0, stream>>>(Y, WFM, bfb, MBUF, out);
}

// Round 4
// 2732.255 us; speedup vs baseline: 1.4624x; 1.3572x over previous
//
#include <hip/hip_runtime.h>
#include <cstdint>
#include <cstddef>

typedef _Float16 f16;
typedef _Float16 f16x8 __attribute__((ext_vector_type(8)));
typedef _Float16 f16x4 __attribute__((ext_vector_type(4)));
typedef float    f32x4 __attribute__((ext_vector_type(4)));

__device__ __forceinline__ void async_ld16(const f16* g, f16* l) {
  __builtin_amdgcn_global_load_lds(
      (const __attribute__((address_space(1))) void*)g,
      (__attribute__((address_space(3))) void*)l, 16, 0, 0);
}

// Full counter drain (vmcnt/lgkmcnt/expcnt = 0).  Placed before barriers that
// guard LDS-DMA completion / LDS reuse — belt-and-braces vs compiler's own
// barrier waitcnt insertion (round-3 post-timing divergence).
__device__ __forceinline__ void full_wait() { __builtin_amdgcn_s_waitcnt(0); }

// ---------------------------------------------------------------------------
// Big-tile conv 3x3 implicit GEMM.  Block tile 256(pix) x 256(co), 4 waves of
// 128x128.  A staged once per ci-chunk as 6-row x 66-px halo (serves all 9
// taps); B double-buffered, prefetched before MFMA, one barrier per tap.
// MODE 0: split-3 (A=hi/lo, W=hi/lo; combos HH+LH+HL), reflect-pad.
// MODE 1: dual-source single-pass (A0*W0 + A1*W1), zero-pad via zpage.
// LDS: A halo 2*6*66*32 f16 = 50688 B; B 2 bufs * 2 str * 256co*32ci = 65536 B.
// NOTE: all global_load_lds LDS destinations are WAVE-UNIFORM (base + HW
// lane*16 scatter) — per-lane LDS pointers are not part of the HW contract.
// ---------------------------------------------------------------------------
template <int MODE>
__global__ __launch_bounds__(256, 1) void conv_big(
    const f16* __restrict__ A0, const f16* __restrict__ A1,
    const f16* __restrict__ W0, const f16* __restrict__ W1,
    float* __restrict__ out, const f16* __restrict__ zpage) {
  __shared__ f16 lsA[25344];   // [stream][hr 0..5][hx 0..65][ci 0..31]
  __shared__ f16 lsB[32768];   // [buf][stream][co 0..255][ci 0..31]
  const int b = blockIdx.y;
  const int mt = blockIdx.x & 15;
  const int nt = blockIdx.x >> 4;
  const int tid = threadIdx.x;
  const int lane = tid & 63;
  const int wid = tid >> 6;
  const int wm = (wid >> 1) * 128;
  const int wn = (wid & 1) * 128;
  const int fr = lane & 15;
  const int fk = (lane >> 4) * 8;
  const int y0 = mt * 4;

  // ---- A-halo slot precompute: 3168 16B-slots, up to 13 per thread ----
  const f16* aptr[13];
#pragma unroll
  for (int r = 0; r < 13; ++r) {
    int slot = r * 256 + tid;
    int cs = slot < 3168 ? slot : 3167;
    int st = cs >= 1584;
    int s1 = cs - st * 1584;
    int hr = s1 / 264;
    int s2 = s1 - hr * 264;
    int hx = s2 >> 2, cig = s2 & 3;
    int iy = y0 - 1 + hr, ix = hx - 1;
    if (MODE == 0) {
      iy = iy < 0 ? -iy : (iy > 63 ? 126 - iy : iy);
      ix = ix < 0 ? -ix : (ix > 63 ? 126 - ix : ix);
      aptr[r] = (st ? A1 : A0) + (((size_t)(b * 4096 + iy * 64 + ix)) << 9) + cig * 8;
    } else {
      bool ok = ((unsigned)iy < 64u) && ((unsigned)ix < 64u);
      aptr[r] = ok ? (st ? A1 : A0) + (((size_t)(b * 4096 + iy * 64 + ix)) << 9) + cig * 8
                   : zpage + cig * 8;
    }
  }
  // ---- B slot precompute: 2048 slots, 8 per thread ----
  const f16* bptr[8];
#pragma unroll
  for (int r = 0; r < 8; ++r) {
    int slot = r * 256 + tid;
    int st = slot >> 10;
    int co = (slot >> 2) & 255;
    int cig = slot & 3;
    bptr[r] = (st ? W1 : W0) + (((size_t)(nt * 256 + co)) << 9) + cig * 8;
  }

  f32x4 acc[8][8];
#pragma unroll
  for (int i = 0; i < 8; ++i)
#pragma unroll
    for (int j = 0; j < 8; ++j) acc[i][j] = f32x4{0.f, 0.f, 0.f, 0.f};

  auto stageA = [&](int ci0) {
#pragma unroll
    for (int r = 0; r < 13; ++r) {
      int slot = r * 256 + tid;
      f16* dst = &lsA[(r * 256 + wid * 64) * 8];  // wave-uniform base
      if (slot < 3168) async_ld16(aptr[r] + ci0, dst);
    }
  };
  auto stageB = [&](int tap, int ci0, int buf) {
#pragma unroll
    for (int r = 0; r < 8; ++r) {
      f16* dst = &lsB[buf * 16384 + (r * 256 + wid * 64) * 8];  // wave-uniform
      async_ld16(bptr[r] + (tap << 18) + ci0, dst);
    }
  };

  int cur = 0;
  stageA(0);
  stageB(0, 0, 0);
  full_wait();
  __syncthreads();

  const int ybase = (wm >> 6) + 1;  // halo row base for this wave (+dy later)
  for (int c = 0; c < 16; ++c) {
    const int ci0 = c * 32;
    for (int tap = 0; tap < 9; ++tap) {
      const int dy = tap / 3 - 1, dx = tap - (tap / 3) * 3 - 1;
      const int nxt = cur ^ 1;
      if (tap < 8)
        stageB(tap + 1, ci0, nxt);
      else if (c < 15)
        stageB(0, ci0 + 32, nxt);

      // A fragments for this tap (halo is tap-invariant within the chunk)
      f16x8 ah[8], al[8];
      const int abase = (ybase + dy) * 2112 + (fr + 1 + dx) * 32 + fk;
#pragma unroll
      for (int i = 0; i < 8; ++i) {
        int ao = abase + (i >> 2) * 2112 + (i & 3) * 512;
        ah[i] = *(const f16x8*)&lsA[ao];
        al[i] = *(const f16x8*)&lsA[ao + 12672];
      }
      const int bbase = cur * 16384 + (wn + fr) * 32 + fk;
#pragma unroll
      for (int j = 0; j < 8; ++j) {
        f16x8 bh = *(const f16x8*)&lsB[bbase + j * 512];
        f16x8 bl = *(const f16x8*)&lsB[bbase + j * 512 + 8192];
#pragma unroll
        for (int i = 0; i < 8; ++i) {
          if (MODE == 0) {
            acc[i][j] = __builtin_amdgcn_mfma_f32_16x16x32_f16(ah[i], bh, acc[i][j], 0, 0, 0);
            acc[i][j] = __builtin_amdgcn_mfma_f32_16x16x32_f16(al[i], bh, acc[i][j], 0, 0, 0);
            acc[i][j] = __builtin_amdgcn_mfma_f32_16x16x32_f16(ah[i], bl, acc[i][j], 0, 0, 0);
          } else {
            acc[i][j] = __builtin_amdgcn_mfma_f32_16x16x32_f16(ah[i], bh, acc[i][j], 0, 0, 0);
            acc[i][j] = __builtin_amdgcn_mfma_f32_16x16x32_f16(al[i], bl, acc[i][j], 0, 0, 0);
          }
        }
      }
      full_wait();      // drain B prefetch DMA + all ds_reads of cur/lsA
      __syncthreads();
      if (tap == 8 && c < 15) {
        stageA(ci0 + 32);
        full_wait();    // drain A-halo DMA before anyone reads it
        __syncthreads();
      }
      cur = nxt;
    }
  }

  // epilogue: D[m = quad*4+reg][n = lane&15]
#pragma unroll
  for (int i = 0; i < 8; ++i) {
#pragma unroll
    for (int rg = 0; rg < 4; ++rg) {
      int m = mt * 256 + wm + i * 16 + (lane >> 4) * 4 + rg;
      size_t rowo = ((size_t)(b * 4096 + m)) << 9;
#pragma unroll
      for (int j = 0; j < 8; ++j) {
        int n = nt * 256 + wn + j * 16 + (lane & 15);
        out[rowo + n] = acc[i][j][rg];
      }
    }
  }
}

// ---------------------------------------------------------------------------
// Patch Gram partials, K-split 4x, pass-fused (HH+LH+HL), gathering directly
// from x NHWC (d-axis permuted: d' = pixel_of_patch*512 + c — Gram-invariant).
// Gp layout: [ks][b][q][k] fp32.
// ---------------------------------------------------------------------------
__global__ __launch_bounds__(256) void corr_fused(const f16* __restrict__ xh,
                                                  const f16* __restrict__ xl,
                                                  float* __restrict__ Gp) {
  __shared__ f16 lsQH[4096], lsQL[4096], lsKH[4096], lsKL[4096];
  const int b = blockIdx.y;
  const int qt = blockIdx.x & 1, kt = (blockIdx.x >> 1) & 1, ks = blockIdx.x >> 2;
  const int tid = threadIdx.x;
  const int lane = tid & 63, wid = tid >> 6;
  const int wm = (wid >> 1) * 64, wn = (wid & 1) * 64;
  const int r4 = lane >> 2, scol = (lane & 3) * 8;
  const int fr = lane & 15, fk = (lane >> 4) * 8;

  f32x4 acc[4][4];
#pragma unroll
  for (int i = 0; i < 4; ++i)
#pragma unroll
    for (int j = 0; j < 4; ++j) acc[i][j] = f32x4{0.f, 0.f, 0.f, 0.f};

  for (int pp = 0; pp < 4; ++pp) {
    const int po = ks * 4 + pp;
    const int ki = po >> 2, kj = po & 3;
    size_t offQ[2], offK[2];
#pragma unroll
    for (int c = 0; c < 2; ++c) {
      int rr = wid * 32 + c * 16 + r4;
      int pq = qt * 128 + rr;
      int pk = kt * 128 + rr;
      int pixq = ((pq >> 4) * 4 + ki) * 64 + (pq & 15) * 4 + kj;
      int pixk = ((pk >> 4) * 4 + ki) * 64 + (pk & 15) * 4 + kj;
      offQ[c] = (((size_t)(b * 4096 + pixq)) << 9) + scol;
      offK[c] = (((size_t)(b * 4096 + pixk)) << 9) + scol;
    }
    for (int c0 = 0; c0 < 512; c0 += 32) {
      __syncthreads();
#pragma unroll
      for (int c = 0; c < 2; ++c) {
        async_ld16(xh + offQ[c] + c0, &lsQH[(wid * 32 + c * 16) * 32]);
        async_ld16(xl + offQ[c] + c0, &lsQL[(wid * 32 + c * 16) * 32]);
        async_ld16(xh + offK[c] + c0, &lsKH[(wid * 32 + c * 16) * 32]);
        async_ld16(xl + offK[c] + c0, &lsKL[(wid * 32 + c * 16) * 32]);
      }
      full_wait();
      __syncthreads();
      f16x8 qh[4], kh[4], t[4];
#pragma unroll
      for (int i = 0; i < 4; ++i)
        qh[i] = *(const f16x8*)&lsQH[(wm + i * 16 + fr) * 32 + fk];
#pragma unroll
      for (int j = 0; j < 4; ++j)
        kh[j] = *(const f16x8*)&lsKH[(wn + j * 16 + fr) * 32 + fk];
#pragma unroll
      for (int i = 0; i < 4; ++i)
#pragma unroll
        for (int j = 0; j < 4; ++j)
          acc[i][j] = __builtin_amdgcn_mfma_f32_16x16x32_f16(qh[i], kh[j],
                                                             acc[i][j], 0, 0, 0);
#pragma unroll
      for (int i = 0; i < 4; ++i)
        t[i] = *(const f16x8*)&lsQL[(wm + i * 16 + fr) * 32 + fk];
#pragma unroll
      for (int i = 0; i < 4; ++i)
#pragma unroll
        for (int j = 0; j < 4; ++j)
          acc[i][j] = __builtin_amdgcn_mfma_f32_16x16x32_f16(t[i], kh[j],
                                                             acc[i][j], 0, 0, 0);
#pragma unroll
      for (int j = 0; j < 4; ++j)
        t[j] = *(const f16x8*)&lsKL[(wn + j * 16 + fr) * 32 + fk];
#pragma unroll
      for (int i = 0; i < 4; ++i)
#pragma unroll
        for (int j = 0; j < 4; ++j)
          acc[i][j] = __builtin_amdgcn_mfma_f32_16x16x32_f16(qh[i], t[j],
                                                             acc[i][j], 0, 0, 0);
    }
  }
#pragma unroll
  for (int i = 0; i < 4; ++i) {
#pragma unroll
    for (int rg = 0; rg < 4; ++rg) {
      int q = qt * 128 + wm + i * 16 + (lane >> 4) * 4 + rg;
      size_t rowo = ((size_t)((ks * 16 + b) * 256 + q)) << 8;
#pragma unroll
      for (int j = 0; j < 4; ++j) {
        int k = kt * 128 + wn + j * 16 + (lane & 15);
        Gp[rowo + k] = acc[i][j][rg];
      }
    }
  }
}

// --------------------------- elementwise kernels ---------------------------

__global__ __launch_bounds__(256) void zsplit_transpose(
    const float* __restrict__ z, f16* __restrict__ zh, f16* __restrict__ zl) {
  __shared__ float t[64][65];
  const int pg = blockIdx.x, cg = blockIdx.y, b = blockIdx.z;
  const int tid = threadIdx.x;
#pragma unroll
  for (int it = 0; it < 16; ++it) {
    int idx = it * 256 + tid;
    int cr = idx >> 6, px = idx & 63;
    t[cr][px] = z[(((size_t)b * 512 + cg * 64 + cr) << 12) + pg * 64 + px];
  }
  __syncthreads();
#pragma unroll
  for (int it = 0; it < 16; ++it) {
    int idx = it * 256 + tid;
    int pr = idx >> 6, cc = idx & 63;
    float v = t[cc][pr];
    f16 h = (f16)v;
    size_t o = (((size_t)b * 4096 + pg * 64 + pr) << 9) + cg * 64 + cc;
    zh[o] = h;
    zl[o] = (f16)(v - (float)h);
  }
}

__global__ void pack_w(const float* __restrict__ w, f16* __restrict__ wh,
                       f16* __restrict__ wl) {
  int i = blockIdx.x * 256 + threadIdx.x;
  if (i >= 9 * 512 * 512) return;
  int ci = i & 511, co = (i >> 9) & 511, tap = i >> 18;
  float v = w[((size_t)(co * 512 + ci)) * 9 + tap];
  f16 h = (f16)v;
  wh[i] = h;
  wl[i] = (f16)(v - (float)h);
}

// wf [512][1025][3][3] -> wfz/wfc [tap][co][ci<512] f16 hi, wfm [co][tap] f32
__global__ void pack_wf_kernel(const float* __restrict__ wf,
                               f16* __restrict__ wfz, f16* __restrict__ wfc,
                               float* __restrict__ wfm) {
  int i = blockIdx.x * 256 + threadIdx.x;
  if (i < 9 * 512 * 1024) {
    int ci = i & 1023, co = (i >> 10) & 511, tap = i >> 19;
    float v = wf[((size_t)co * 1025 + ci) * 9 + tap];
    f16 h = (f16)v;
    int o = ((tap * 512 + co) << 9) + (ci & 511);
    if (ci < 512)
      wfz[o] = h;
    else
      wfc[o] = h;
  } else {
    int j = i - 9 * 512 * 1024;
    if (j < 512 * 9) {
      int co = j / 9, tap = j - co * 9;
      wfm[j] = wf[((size_t)co * 1025 + 1024) * 9 + tap];
    }
  }
}

__global__ void mask_resize(const float* __restrict__ mask, float* __restrict__ M) {
  int i = blockIdx.x * 256 + threadIdx.x;
  if (i >= 16 * 4096) return;
  int b = i >> 12, oy = (i >> 6) & 63, ox = i & 63;
  int y0 = max(4 * oy - 2, 0), y1 = min(4 * oy + 5, 255);
  int x0 = max(4 * ox - 2, 0), x1 = min(4 * ox + 5, 255);
  const float* mb = mask + ((size_t)b << 16);
  float r = 0.f;
  for (int jy = y0; jy <= y1; ++jy) {
    for (int jx = x0; jx <= x1; ++jx) {
      if (mb[(jy << 8) + jx] != 0.f) {
        r = 1.f;
        jy = 256;
        break;
      }
    }
  }
  M[i] = r;
}

__global__ void patch_flag(const float* __restrict__ M, float* __restrict__ nonmask) {
  int i = blockIdx.x * 256 + threadIdx.x;
  if (i >= 16 * 256) return;
  int b = i >> 8, p = i & 255;
  int py = p >> 4, px = p & 15;
  int cnt = 0;
  for (int ki = 0; ki < 4; ++ki)
    for (int kj = 0; kj < 4; ++kj)
      cnt += (M[(b << 12) + ((py * 4 + ki) << 6) + px * 4 + kj] > 0.5f) ? 1 : 0;
  nonmask[i] = (cnt >= 10) ? 1.f : 0.f;
}

// InstanceNorm stage 1: fully-coalesced partial sums. grid (16 pg, 16 b).
__global__ __launch_bounds__(256) void in_stats1(const float* __restrict__ y,
                                                 float* __restrict__ parts) {
  const int pg = blockIdx.x, b = blockIdx.y;
  const int tid = threadIdx.x;
  const int c4 = (tid & 127) << 2;
  const int ph = tid >> 7;
  const float* base = y + (((size_t)b) << 21) + (((size_t)(pg * 256 + ph)) << 9) + c4;
  float s[4] = {0, 0, 0, 0}, q[4] = {0, 0, 0, 0};
  for (int k = 0; k < 128; ++k) {
    float4 v = *(const float4*)(base + ((size_t)k << 10));
    float vv[4] = {v.x, v.y, v.z, v.w};
#pragma unroll
    for (int u = 0; u < 4; ++u) {
      s[u] += vv[u];
      q[u] += vv[u] * vv[u];
    }
  }
  __shared__ float red[2048];
#pragma unroll
  for (int u = 0; u < 4; ++u) {
    red[tid * 8 + u] = s[u];
    red[tid * 8 + 4 + u] = q[u];
  }
  __syncthreads();
  if (tid < 128) {
    float* o = &parts[(((size_t)(b * 16 + pg) * 512) + c4) * 2];
#pragma unroll
    for (int u = 0; u < 4; ++u) {
      o[u * 2] = red[tid * 8 + u] + red[(tid + 128) * 8 + u];
      o[u * 2 + 1] = red[tid * 8 + 4 + u] + red[(tid + 128) * 8 + 4 + u];
    }
  }
}

// InstanceNorm stage 2: reduce 16 pixel-groups -> (mean, rstd). grid (2, 16).
__global__ void in_stats2(const float* __restrict__ parts, float2* __restrict__ stats) {
  const int b = blockIdx.y;
  const int c = blockIdx.x * 256 + threadIdx.x;
  float s = 0.f, q = 0.f;
  for (int pg = 0; pg < 16; ++pg) {
    size_t o = (((size_t)(b * 16 + pg) * 512) + c) * 2;
    s += parts[o];
    q += parts[o + 1];
  }
  float mean = s * (1.f / 4096.f);
  float var = q * (1.f / 4096.f) - mean * mean;
  stats[b * 512 + c] = make_float2(mean, 1.f / sqrtf(var + 1e-5f));
}

__global__ __launch_bounds__(256) void h_build(const float* __restrict__ y,
                                               const float2* __restrict__ stats,
                                               f16* __restrict__ hh,
                                               f16* __restrict__ hl) {
  size_t i = (size_t)blockIdx.x * 256 + threadIdx.x;
  if (i >= 8388608u) return;
  float4 v = ((const float4*)y)[i];
  size_t e = i << 2;
  int c = (int)(e & 511);
  int b = (int)(e >> 21);
  const float2* st = stats + b * 512 + c;
  float vv[4] = {v.x, v.y, v.z, v.w};
  f16x4 oh, ol;
#pragma unroll
  for (int j = 0; j < 4; ++j) {
    float2 s = st[j];
    float h = fmaxf((vv[j] - s.x) * s.y, 0.f);
    f16 hi = (f16)h;
    oh[j] = hi;
    ol[j] = (f16)(h - (float)hi);
  }
  ((f16x4*)hh)[i] = oh;
  ((f16x4*)hl)[i] = ol;
}

__global__ __launch_bounds__(256) void x_build(const float* __restrict__ y,
                                               const float2* __restrict__ stats,
                                               const f16* __restrict__ zh,
                                               const f16* __restrict__ zl,
                                               f16* __restrict__ xh,
                                               f16* __restrict__ xl) {
  size_t i = (size_t)blockIdx.x * 256 + threadIdx.x;
  if (i >= 8388608u) return;
  float4 v = ((const float4*)y)[i];
  f16x4 zhv = ((const f16x4*)zh)[i];
  f16x4 zlv = ((const f16x4*)zl)[i];
  size_t e = i << 2;
  int c = (int)(e & 511);
  int b = (int)(e >> 21);
  const float2* st = stats + b * 512 + c;
  float vv[4] = {v.x, v.y, v.z, v.w};
  f16x4 oh, ol;
#pragma unroll
  for (int j = 0; j < 4; ++j) {
    float2 s = st[j];
    float xv = (float)zhv[j] + (float)zlv[j] + (vv[j] - s.x) * s.y;
    f16 hi = (f16)xv;
    oh[j] = hi;
    ol[j] = (f16)(xv - (float)hi);
  }
  ((f16x4*)xh)[i] = oh;
  ((f16x4*)xl)[i] = ol;
}

// Per-patch L2 norm of x.
__global__ __launch_bounds__(256) void patch_norms(const f16* __restrict__ xh,
                                                   const f16* __restrict__ xl,
                                                   float* __restrict__ norms) {
  __shared__ float red[256];
  const int p = blockIdx.x, b = blockIdx.y;
  const int tid = threadIdx.x;
  const int py = p >> 4, px = p & 15;
  const int po = tid >> 4, c0 = (tid & 15) * 32;
  const int ki = po >> 2, kj = po & 3;
  const size_t src =
      (((size_t)b * 4096 + (py * 4 + ki) * 64 + px * 4 + kj) << 9) + c0;
  float ss = 0.f;
#pragma unroll
  for (int v = 0; v < 4; ++v) {
    f16x8 a = *(const f16x8*)(xh + src + v * 8);
    f16x8 bb = *(const f16x8*)(xl + src + v * 8);
#pragma unroll
    for (int k = 0; k < 8; ++k) {
      float t = (float)a[k] + (float)bb[k];
      ss += t * t;
    }
  }
  red[tid] = ss;
  __syncthreads();
  for (int st = 128; st >= 1; st >>= 1) {
    if (tid < st) red[tid] += red[tid + st];
    __syncthreads();
  }
  if (tid == 0) norms[b * 256 + p] = fmaxf(sqrtf(red[0]), 1e-12f);
}

// argmax over k of (sum of 4 K-slice partials)/norm_k, masked; first-index tie.
__global__ __launch_bounds__(256) void argmax_kernel(
    const float* __restrict__ Gp, const float* __restrict__ norms,
    const float* __restrict__ nonmask, int* __restrict__ marg) {
  const int q = blockIdx.x, b = blockIdx.y;
  const int t = threadIdx.x;
  float nm = nonmask[b * 256 + t];
  float v;
  if (nm == 1.f) {
    v = -1e9f;
  } else {
    size_t o = (((size_t)b * 256 + q) << 8) + t;
    const size_t step = (size_t)16 * 256 * 256;
    double s = (double)Gp[o] + (double)Gp[o + step] + (double)Gp[o + 2 * step] +
               (double)Gp[o + 3 * step];
    v = (float)(s / (double)norms[b * 256 + t]);
  }
  __shared__ float bv[256];
  __shared__ int bi[256];
  bv[t] = v;
  bi[t] = t;
  __syncthreads();
  for (int st = 128; st >= 1; st >>= 1) {
    if (t < st) {
      float v2 = bv[t + st];
      int i2 = bi[t + st];
      if (v2 > bv[t] || (v2 == bv[t] && i2 < bi[t])) {
        bv[t] = v2;
        bi[t] = i2;
      }
    }
    __syncthreads();
  }
  if (t == 0) marg[b * 256 + q] = bi[0];
}

__global__ void comp_build(const f16* __restrict__ xh, const int* __restrict__ marg,
                           f16* __restrict__ ch) {
  size_t i = (size_t)blockIdx.x * 256 + threadIdx.x;
  if (i >= (size_t)16 * 4096 * 64) return;
  int c8 = (int)(i & 63);
  int pix = (int)((i >> 6) & 4095);
  int b = (int)(i >> 18);
  int y = pix >> 6, x = pix & 63;
  int q = ((y >> 2) << 4) + (x >> 2);
  int k = marg[b * 256 + q];
  int sy = ((k >> 4) << 2) + (y & 3);
  int sx = ((k & 15) << 2) + (x & 3);
  size_t src = (((size_t)b * 4096 + sy * 64 + sx) << 9) + c8 * 8;
  size_t dst = (((size_t)b * 4096 + pix) << 9) + c8 * 8;
  *(f16x8*)(ch + dst) = *(const f16x8*)(xh + src);
}

__global__ __launch_bounds__(256) void finish_kernel(
    const float* __restrict__ acc, const float* __restrict__ wfm,
    const float* __restrict__ bias, const float* __restrict__ M,
    float* __restrict__ out) {
  __shared__ float ls[64][65];
  __shared__ float lw[64 * 9];
  __shared__ float lm[3][66];
  const int y = blockIdx.x, cg = blockIdx.y, b = blockIdx.z;
  const int tid = threadIdx.x;
#pragma unroll
  for (int it = 0; it < 16; ++it) {
    int idx = it * 256 + tid;
    int px = idx >> 6, co = idx & 63;
    ls[px][co] = acc[(((size_t)b * 4096 + y * 64 + px) << 9) + cg * 64 + co];
  }
  if (tid < 192) {
#pragma unroll
    for (int j = 0; j < 3; ++j) lw[tid * 3 + j] = wfm[(cg * 64) * 9 + tid * 3 + j];
  }
  if (tid < 198) {
    int row = tid / 66, col = tid % 66;
    int gy = y - 1 + row, gx = col - 1;
    float mv = 0.f;
    if ((unsigned)gy < 64u && (unsigned)gx < 64u)
      mv = M[(b << 12) + (gy << 6) + gx];
    lm[row][col] = mv;
  }
  __syncthreads();
#pragma unroll
  for (int it = 0; it < 16; ++it) {
    int idx = it * 256 + tid;
    int co = idx >> 6, px = idx & 63;
    float s = ls[px][co] + bias[cg * 64 + co];
#pragma unroll
    for (int ky = 0; ky < 3; ++ky)
#pragma unroll
      for (int kx = 0; kx < 3; ++kx)
        s += lw[co * 9 + ky * 3 + kx] * lm[ky][px + kx];
    out[(((size_t)b * 512 + cg * 64 + co) << 12) + y * 64 + px] = s;
  }
}

// ---------------------------------------------------------------------------
extern "C" void kernel_launch(void* const* d_in, const int* in_sizes, int n_in,
                              void* d_out, int out_size, void* d_ws,
                              size_t ws_size, hipStream_t stream) {
  const float* z = (const float*)d_in[0];
  const float* mask = (const float*)d_in[1];
  const float* w1 = (const float*)d_in[2];
  const float* w2 = (const float*)d_in[4];
  const float* wf = (const float*)d_in[6];
  const float* bfb = (const float*)d_in[7];
  float* out = (float*)d_out;

  char* ws = (char*)d_ws;
  size_t off = 0;
  auto alloc = [&](size_t bytes) -> void* {
    void* p = ws + off;
    off += (bytes + 255) & ~(size_t)255;
    return p;
  };
  f16* ZH = (f16*)alloc(67108864);
  f16* ZL = (f16*)alloc(67108864);   // G partials alias here after x_build
  f16* HXH = (f16*)alloc(67108864);  // h1 then x (hi)
  f16* HXL = (f16*)alloc(67108864);  // h1/x (lo), then composed (hi)
  float* Y = (float*)alloc(134217728);
  f16* W1H = (f16*)alloc(4718592);
  f16* W1L = (f16*)alloc(4718592);
  f16* W2H = (f16*)alloc(4718592);
  f16* W2L = (f16*)alloc(4718592);
  f16* WFZ = (f16*)alloc(4718592);
  f16* WFC = (f16*)alloc(4718592);
  float* WFM = (float*)alloc(18432);
  float2* STATS = (float2*)alloc(65536);
  float* MBUF = (float*)alloc(262144);
  float* NONMASK = (float*)alloc(16384);
  float* NORMS = (float*)alloc(16384);
  int* MAXARG = (int*)alloc(16384);
  float* PARTS = (float*)alloc(1048576);
  f16* ZPAGE = (f16*)alloc(4096);
  if (ws_size < off) return;

  float* G = (float*)ZL;  // 16.8 MB of 64 MB, live only corr->argmax

  hipMemsetAsync(ZPAGE, 0, 4096, stream);

  zsplit_transpose<<<dim3(64, 8, 16), 256, 0, stream>>>(z, ZH, ZL);
  pack_w<<<9216, 256, 0, stream>>>(w1, W1H, W1L);
  pack_w<<<9216, 256, 0, stream>>>(w2, W2H, W2L);
  pack_wf_kernel<<<18450, 256, 0, stream>>>(wf, WFZ, WFC, WFM);
  mask_resize<<<256, 256, 0, stream>>>(mask, MBUF);
  patch_flag<<<16, 256, 0, stream>>>(MBUF, NONMASK);

  conv_big<0><<<dim3(32, 16), 256, 0, stream>>>(ZH, ZL, W1H, W1L, Y, ZPAGE);
  in_stats1<<<dim3(16, 16), 256, 0, stream>>>(Y, PARTS);
  in_stats2<<<dim3(2, 16), 256, 0, stream>>>(PARTS, STATS);
  h_build<<<32768, 256, 0, stream>>>(Y, STATS, HXH, HXL);
  conv_big<0><<<dim3(32, 16), 256, 0, stream>>>(HXH, HXL, W2H, W2L, Y, ZPAGE);
  in_stats1<<<dim3(16, 16), 256, 0, stream>>>(Y, PARTS);
  in_stats2<<<dim3(2, 16), 256, 0, stream>>>(PARTS, STATS);
  x_build<<<32768, 256, 0, stream>>>(Y, STATS, ZH, ZL, HXH, HXL);

  patch_norms<<<dim3(256, 16), 256, 0, stream>>>(HXH, HXL, NORMS);
  corr_fused<<<dim3(16, 16), 256, 0, stream>>>(HXH, HXL, G);
  argmax_kernel<<<dim3(256, 16), 256, 0, stream>>>(G, NORMS, NONMASK, MAXARG);
  comp_build<<<16384, 256, 0, stream>>>(HXH, MAXARG, HXL);

  conv_big<1><<<dim3(32, 16), 256, 0, stream>>>(ZH, HXL, WFZ, WFC, Y, ZPAGE);
  finish_kernel<<<dim3(64, 8, 16), 256, 0, stream>>>(Y, WFM, bfb, MBUF, out);
}